// Round 1
// baseline (799.186 us; speedup 1.0000x reference)
//
#include <hip/hip_runtime.h>
#include <hip/hip_bf16.h>
#include <math.h>
#include <stdint.h>

typedef __bf16 bf16_t;
typedef __bf16 bf16x8 __attribute__((ext_vector_type(8)));
typedef __bf16 bf16x4 __attribute__((ext_vector_type(4)));
typedef float  f32x4  __attribute__((ext_vector_type(4)));

#define BATCH   4096
#define DM      1024
#define DFF     2048
#define NTILES  8

__device__ __forceinline__ float gelu_exact(float x) {
    return 0.5f * x * (1.0f + erff(x * 0.70710678118654752440f));
}

__device__ __forceinline__ void async_ld16(const bf16_t* g, bf16_t* l) {
    __builtin_amdgcn_global_load_lds(
        (const __attribute__((address_space(1))) void*)g,
        (__attribute__((address_space(3))) void*)l, 16, 0, 0);
}

__device__ __forceinline__ f32x4 mfma16(bf16x8 a, bf16x8 b, f32x4 c) {
    return __builtin_amdgcn_mfma_f32_16x16x32_bf16(a, b, c, 0, 0, 0);
}

// ---------------- x -> bf16 hi/lo split ----------------
__global__ __launch_bounds__(256) void cvt_x_kernel(
    const float* __restrict__ x, bf16_t* __restrict__ xh, bf16_t* __restrict__ xl) {
    int i = blockIdx.x * 256 + threadIdx.x;           // float4 index
    float4 v = ((const float4*)x)[i];
    bf16x4 h, l;
    float f;
    f = v.x; h[0] = (bf16_t)f; l[0] = (bf16_t)(f - (float)h[0]);
    f = v.y; h[1] = (bf16_t)f; l[1] = (bf16_t)(f - (float)h[1]);
    f = v.z; h[2] = (bf16_t)f; l[2] = (bf16_t)(f - (float)h[2]);
    f = v.w; h[3] = (bf16_t)f; l[3] = (bf16_t)(f - (float)h[3]);
    *(bf16x4*)(xh + (size_t)i * 4) = h;
    *(bf16x4*)(xl + (size_t)i * 4) = l;
}

// ---------------- transpose + convert: in f32 (K,N) row-major -> out bf16 (N,K) ----------------
template<bool LO>
__global__ __launch_bounds__(256) void tconv_kernel(
    const float* __restrict__ in, bf16_t* __restrict__ outh, bf16_t* __restrict__ outl,
    int K, int N) {
    __shared__ float t[32][33];
    size_t msz = (size_t)K * N;
    int mat = blockIdx.z;
    const float* src = in + msz * mat;
    int n0 = blockIdx.x * 32, k0 = blockIdx.y * 32;
    int tx = threadIdx.x & 31, ty = threadIdx.x >> 5;   // ty in 0..7
#pragma unroll
    for (int s = 0; s < 4; ++s)
        t[ty + 8 * s][tx] = src[(size_t)(k0 + ty + 8 * s) * N + (n0 + tx)];
    __syncthreads();
#pragma unroll
    for (int s = 0; s < 4; ++s) {
        float v = t[tx][ty + 8 * s];
        bf16_t h = (bf16_t)v;
        size_t oi = msz * mat + (size_t)(n0 + ty + 8 * s) * K + (k0 + tx);
        outh[oi] = h;
        if constexpr (LO) outl[oi] = (bf16_t)(v - (float)h);
    }
}

// ---------------- GEMM: C[M,N] = A[M,K] @ Bt[N,K]^T (+bias, opt gelu) ----------------
// 128x128 tile, BK=32, 256 threads (4 waves, 2x2), m97-style global_load_lds staging.
template<bool SPLIT, bool GATHER, bool GELU, bool SCATTER, bool OUTF32>
__global__ __launch_bounds__(256) void gemm_kernel(
    const bf16_t* __restrict__ A, const bf16_t* __restrict__ Alo,
    const bf16_t* __restrict__ Bt, const bf16_t* __restrict__ Btlo,
    const float* __restrict__ bias,
    float* __restrict__ outF, bf16_t* __restrict__ outB,
    const int* __restrict__ perm, const int* __restrict__ counts,
    int M, int N, int K) {
    const int tile = blockIdx.z;
    int cnt = M;
    const int* permT = nullptr;
    if constexpr (GATHER) {
        cnt = counts[tile];
        permT = perm + tile * BATCH;
        if ((int)blockIdx.x * 128 >= cnt) return;
    }
    Bt   += (size_t)tile * K * N;
    if constexpr (SPLIT) Btlo += (size_t)tile * K * N;
    bias += (size_t)tile * N;

    __shared__ __align__(16) bf16_t As[128 * 32];
    __shared__ __align__(16) bf16_t Bs[128 * 32];
    __shared__ __align__(16) bf16_t Asl[SPLIT ? 128 * 32 : 8];
    __shared__ __align__(16) bf16_t Bsl[SPLIT ? 128 * 32 : 8];

    const int lane = threadIdx.x & 63;
    const int wave = threadIdx.x >> 6;
    const int wm = wave & 1, wn = wave >> 1;
    const int rb = blockIdx.x * 128;
    const int nb = blockIdx.y * 128;

    size_t aoff[2], boff[2];
#pragma unroll
    for (int r = 0; r < 2; ++r) {
        int seg = r * 4 + wave;
        int row = seg * 16 + (lane >> 2);
        int arow;
        if constexpr (GATHER) {
            int pos = rb + row;
            if (pos > cnt - 1) pos = cnt - 1;
            arow = permT[pos];
        } else {
            arow = rb + row;
        }
        aoff[r] = (size_t)arow * K + (size_t)((lane & 3) * 8);
        boff[r] = (size_t)(nb + row) * K + (size_t)((lane & 3) * 8);
    }

    f32x4 acc[4][4];
#pragma unroll
    for (int i = 0; i < 4; ++i)
#pragma unroll
        for (int j = 0; j < 4; ++j) acc[i][j] = (f32x4){0.f, 0.f, 0.f, 0.f};

    const int lr = lane & 15, lq = lane >> 4;

    for (int k0 = 0; k0 < K; k0 += 32) {
#pragma unroll
        for (int r = 0; r < 2; ++r) {
            int seg = r * 4 + wave;
            async_ld16(A  + aoff[r] + k0, &As[seg * 512]);
            async_ld16(Bt + boff[r] + k0, &Bs[seg * 512]);
            if constexpr (SPLIT) {
                async_ld16(Alo  + aoff[r] + k0, &Asl[seg * 512]);
                async_ld16(Btlo + boff[r] + k0, &Bsl[seg * 512]);
            }
        }
        __syncthreads();

        bf16x8 af[4], bfr[4], afl[4], bfl[4];
#pragma unroll
        for (int i = 0; i < 4; ++i) {
            af[i]  = *(const bf16x8*)&As[(wm * 64 + i * 16 + lr) * 32 + lq * 8];
            bfr[i] = *(const bf16x8*)&Bs[(wn * 64 + i * 16 + lr) * 32 + lq * 8];
            if constexpr (SPLIT) {
                afl[i] = *(const bf16x8*)&Asl[(wm * 64 + i * 16 + lr) * 32 + lq * 8];
                bfl[i] = *(const bf16x8*)&Bsl[(wn * 64 + i * 16 + lr) * 32 + lq * 8];
            }
        }
#pragma unroll
        for (int i = 0; i < 4; ++i)
#pragma unroll
            for (int j = 0; j < 4; ++j) {
                acc[i][j] = mfma16(af[i], bfr[j], acc[i][j]);
                if constexpr (SPLIT) {
                    acc[i][j] = mfma16(af[i], bfl[j], acc[i][j]);
                    acc[i][j] = mfma16(afl[i], bfr[j], acc[i][j]);
                    acc[i][j] = mfma16(afl[i], bfl[j], acc[i][j]);
                }
            }
        __syncthreads();
    }

    // epilogue: C row = (lane>>4)*4 + reg, col = lane&15 (m89/m91-verified)
#pragma unroll
    for (int i = 0; i < 4; ++i) {
#pragma unroll
        for (int j = 0; j < 4; ++j) {
#pragma unroll
            for (int r = 0; r < 4; ++r) {
                int m = wm * 64 + i * 16 + lq * 4 + r;
                int n = wn * 64 + j * 16 + lr;
                int pos = rb + m;
                if constexpr (GATHER) { if (pos >= cnt) continue; }
                int grow;
                if constexpr (SCATTER) grow = permT[pos];
                else                   grow = pos;
                int gn = nb + n;
                float v = acc[i][j][r] + bias[gn];
                if constexpr (GELU) v = gelu_exact(v);
                if constexpr (OUTF32) outF[(size_t)grow * N + gn] = v;
                else                  outB[(size_t)grow * N + gn] = (bf16_t)v;
            }
        }
    }
}

// ---------------- router layer2 + argmax + routing lists ----------------
__global__ __launch_bounds__(256) void router2_kernel(
    const float* __restrict__ Hr, const float* __restrict__ Wr2, const float* __restrict__ br2,
    float* __restrict__ outLog, float* __restrict__ outIdx,
    int* __restrict__ counts, int* __restrict__ perm) {
    int lane = threadIdx.x & 63, wave = threadIdx.x >> 6;
    int row = blockIdx.x * 4 + wave;
    const float* h = Hr + (size_t)row * DM;
    float acc[8];
#pragma unroll
    for (int j = 0; j < 8; ++j) acc[j] = 0.f;
    for (int k = lane; k < DM; k += 64) {
        float hv = h[k];
        const float4* w = (const float4*)(Wr2 + (size_t)k * 8);
        float4 w0 = w[0], w1 = w[1];
        acc[0] += hv * w0.x; acc[1] += hv * w0.y; acc[2] += hv * w0.z; acc[3] += hv * w0.w;
        acc[4] += hv * w1.x; acc[5] += hv * w1.y; acc[6] += hv * w1.z; acc[7] += hv * w1.w;
    }
#pragma unroll
    for (int off = 32; off; off >>= 1)
#pragma unroll
        for (int j = 0; j < 8; ++j) acc[j] += __shfl_down(acc[j], off);
    if (lane == 0) {
        float best = -1e30f; int bi = 0;
        float lg[8];
#pragma unroll
        for (int j = 0; j < 8; ++j) {
            float v = (acc[j] + br2[j]) * 2.0f;   // /TEMPERATURE, T=0.5
            lg[j] = v;
            if (v > best) { best = v; bi = j; }   // strict > == first-max (jnp.argmax)
        }
#pragma unroll
        for (int j = 0; j < 8; ++j) outLog[(size_t)row * 8 + j] = lg[j];
        outIdx[row] = (float)bi;
        int p = atomicAdd(&counts[bi], 1);
        perm[bi * BATCH + p] = row;
    }
}

// ---------------- host launch ----------------
extern "C" void kernel_launch(void* const* d_in, const int* in_sizes, int n_in,
                              void* d_out, int out_size, void* d_ws, size_t ws_size,
                              hipStream_t stream) {
    const float* x   = (const float*)d_in[0];
    const float* Wr1 = (const float*)d_in[1];
    const float* br1 = (const float*)d_in[2];
    const float* Wr2 = (const float*)d_in[3];
    const float* br2 = (const float*)d_in[4];
    const float* W1  = (const float*)d_in[5];
    const float* b1  = (const float*)d_in[6];
    const float* W2  = (const float*)d_in[7];
    const float* b2  = (const float*)d_in[8];
    const float* Wo  = (const float*)d_in[9];
    const float* bo  = (const float*)d_in[10];

    char* ws = (char*)d_ws;
    size_t o = 0;
    auto carve = [&](size_t bytes) { char* p = ws + o; o = (o + bytes + 255) & ~(size_t)255; return p; };
    bf16_t* Wr1h = (bf16_t*)carve((size_t)DM * DM * 2);
    bf16_t* Wr1l = (bf16_t*)carve((size_t)DM * DM * 2);
    bf16_t* Wot  = (bf16_t*)carve((size_t)DM * DM * 2);
    bf16_t* W1t  = (bf16_t*)carve((size_t)NTILES * DM * DFF * 2);
    bf16_t* W2t  = (bf16_t*)carve((size_t)NTILES * DM * DFF * 2);
    bf16_t* xh   = (bf16_t*)carve((size_t)BATCH * DM * 2);
    bf16_t* xl   = (bf16_t*)carve((size_t)BATCH * DM * 2);
    bf16_t* H1   = (bf16_t*)carve((size_t)BATCH * DFF * 2);
    bf16_t* sel  = (bf16_t*)carve((size_t)BATCH * DM * 2);
    float*  Hr   = (float*)carve((size_t)BATCH * DM * 4);
    int*    counts = (int*)carve(NTILES * sizeof(int));
    int*    perm   = (int*)carve((size_t)NTILES * BATCH * sizeof(int));

    float* outMain = (float*)d_out;
    float* outIdx  = outMain + (size_t)BATCH * DM;
    float* outLog  = outIdx + BATCH;

    hipMemsetAsync(counts, 0, NTILES * sizeof(int), stream);

    cvt_x_kernel<<<BATCH * DM / 4 / 256, 256, 0, stream>>>(x, xh, xl);
    tconv_kernel<true ><<<dim3(DM / 32, DM / 32, 1), 256, 0, stream>>>(Wr1, Wr1h, Wr1l, DM, DM);
    tconv_kernel<false><<<dim3(DM / 32, DM / 32, 1), 256, 0, stream>>>(Wo, Wot, nullptr, DM, DM);
    tconv_kernel<false><<<dim3(DFF / 32, DM / 32, NTILES), 256, 0, stream>>>(W1, W1t, nullptr, DM, DFF);
    tconv_kernel<false><<<dim3(DM / 32, DFF / 32, NTILES), 256, 0, stream>>>(W2, W2t, nullptr, DFF, DM);

    // router layer 1: Hr = gelu(x @ Wr1 + br1), hi/lo split for fp32-class accuracy
    gemm_kernel<true, false, true, false, true><<<dim3(BATCH / 128, DM / 128, 1), 256, 0, stream>>>(
        xh, xl, Wr1h, Wr1l, br1, Hr, nullptr, nullptr, nullptr, BATCH, DM, DM);

    router2_kernel<<<BATCH / 4, 256, 0, stream>>>(Hr, Wr2, br2, outLog, outIdx, counts, perm);

    // expert layer 1: H1[token] = gelu(x[token] @ W1[t] + b1[t]), gathered+scattered
    gemm_kernel<false, true, true, true, false><<<dim3(BATCH / 128, DFF / 128, NTILES), 256, 0, stream>>>(
        xh, nullptr, W1t, nullptr, b1, nullptr, H1, perm, counts, BATCH, DFF, DM);

    // expert layer 2: sel[token] = H1[token] @ W2[t] + b2[t]
    gemm_kernel<false, true, false, true, false><<<dim3(BATCH / 128, DM / 128, NTILES), 256, 0, stream>>>(
        H1, nullptr, W2t, nullptr, b2, nullptr, sel, perm, counts, BATCH, DM, DFF);

    // output projection: out = sel @ Wo + bo
    gemm_kernel<false, false, false, false, true><<<dim3(BATCH / 128, DM / 128, 1), 256, 0, stream>>>(
        sel, nullptr, Wot, nullptr, bo, outMain, nullptr, nullptr, nullptr, BATCH, DM, DM);
}

// Round 2
// 503.484 us; speedup vs baseline: 1.5873x; 1.5873x over previous
//
#include <hip/hip_runtime.h>
#include <hip/hip_bf16.h>
#include <math.h>
#include <stdint.h>

typedef __bf16 bf16_t;
typedef __bf16 bf16x2 __attribute__((ext_vector_type(2)));
typedef __bf16 bf16x4 __attribute__((ext_vector_type(4)));
typedef __bf16 bf16x8 __attribute__((ext_vector_type(8)));
typedef float  f32x4  __attribute__((ext_vector_type(4)));

#define BATCH   4096
#define DM      1024
#define DFF     2048
#define NTILES  8
#define MAXXB   40   // max compacted x-blocks: 32 + 7 partials, rounded up

__device__ __forceinline__ float gelu_exact(float x) {
    return 0.5f * x * (1.0f + erff(x * 0.70710678118654752440f));
}

__device__ __forceinline__ void async_ld16(const bf16_t* g, bf16_t* l) {
    __builtin_amdgcn_global_load_lds(
        (const __attribute__((address_space(1))) void*)g,
        (__attribute__((address_space(3))) void*)l, 16, 0, 0);
}

__device__ __forceinline__ f32x4 mfma16(bf16x8 a, bf16x8 b, f32x4 c) {
    return __builtin_amdgcn_mfma_f32_16x16x32_bf16(a, b, c, 0, 0, 0);
}

// ---------------- x -> bf16 hi/lo split ----------------
__global__ __launch_bounds__(256) void cvt_x_kernel(
    const float* __restrict__ x, bf16_t* __restrict__ xh, bf16_t* __restrict__ xl) {
    int i = blockIdx.x * 256 + threadIdx.x;           // float4 index
    float4 v = ((const float4*)x)[i];
    bf16x4 h, l;
    float f;
    f = v.x; h[0] = (bf16_t)f; l[0] = (bf16_t)(f - (float)h[0]);
    f = v.y; h[1] = (bf16_t)f; l[1] = (bf16_t)(f - (float)h[1]);
    f = v.z; h[2] = (bf16_t)f; l[2] = (bf16_t)(f - (float)h[2]);
    f = v.w; h[3] = (bf16_t)f; l[3] = (bf16_t)(f - (float)h[3]);
    *(bf16x4*)(xh + (size_t)i * 4) = h;
    *(bf16x4*)(xl + (size_t)i * 4) = l;
}

// ---------------- transpose + convert: in f32 (K,N) row-major -> out bf16 (N,K) ----------------
template<bool LO>
__global__ __launch_bounds__(256) void tconv_kernel(
    const float* __restrict__ in, bf16_t* __restrict__ outh, bf16_t* __restrict__ outl,
    int K, int N) {
    __shared__ float t[32][33];
    size_t msz = (size_t)K * N;
    int mat = blockIdx.z;
    const float* src = in + msz * mat;
    int n0 = blockIdx.x * 32, k0 = blockIdx.y * 32;
    int tx = threadIdx.x & 31, ty = threadIdx.x >> 5;   // ty in 0..7
#pragma unroll
    for (int s = 0; s < 4; ++s)
        t[ty + 8 * s][tx] = src[(size_t)(k0 + ty + 8 * s) * N + (n0 + tx)];  // t[k][n]
    __syncthreads();
    int kh = threadIdx.x & 15;   // k pair
    int nl = threadIdx.x >> 4;   // 0..15
#pragma unroll
    for (int s = 0; s < 2; ++s) {
        int n = nl + 16 * s;
        float v0 = t[kh * 2][n], v1 = t[kh * 2 + 1][n];
        bf16x2 hh; hh[0] = (bf16_t)v0; hh[1] = (bf16_t)v1;
        size_t oi = msz * mat + (size_t)(n0 + n) * K + k0 + kh * 2;
        *(bf16x2*)(outh + oi) = hh;
        if constexpr (LO) {
            bf16x2 ll; ll[0] = (bf16_t)(v0 - (float)hh[0]); ll[1] = (bf16_t)(v1 - (float)hh[1]);
            *(bf16x2*)(outl + oi) = ll;
        }
    }
}

// ---------------- routing plan: compact (tile, xblock) list ----------------
__global__ void plan_kernel(const int* __restrict__ counts,
                            int* __restrict__ plan, int* __restrict__ ntotal) {
    if (threadIdx.x == 0) {
        int b = 0;
        for (int t = 0; t < NTILES; ++t) {
            int nb = (counts[t] + 127) >> 7;
            for (int i = 0; i < nb; ++i) plan[b++] = (t << 16) | i;
        }
        *ntotal = b;
    }
}

// ---------------- GEMM: C[M,N] = A[M,K] @ Bt[N,K]^T (+bias, opt gelu) ----------------
// 128x128 tile, BK=32, 256 threads (4 waves, 2x2), global_load_lds width-16 staging.
// LDS layout per 16-row segment: cell=lane, holds row (lane&15), k-chunk (lane>>4)*8.
// Reads stride 16B -> 2-way bank aliasing only (free).
template<bool SPLIT, bool GATHER, bool GELU, bool SCATTER, bool OUTF32>
__global__ __launch_bounds__(256) void gemm_kernel(
    const bf16_t* __restrict__ A, const bf16_t* __restrict__ Alo,
    const bf16_t* __restrict__ Bt, const bf16_t* __restrict__ Btlo,
    const float* __restrict__ bias,
    float* __restrict__ outF, bf16_t* __restrict__ outB,
    const int* __restrict__ perm, const int* __restrict__ counts,
    const int* __restrict__ plan, const int* __restrict__ ntotal,
    int M, int N, int K) {
    int tile, rb, cnt = M;
    const int* permT = nullptr;
    if constexpr (GATHER) {
        if ((int)blockIdx.x >= *ntotal) return;
        int p = plan[blockIdx.x];
        tile = p >> 16;
        rb = (p & 0xffff) * 128;
        cnt = counts[tile];
        permT = perm + tile * BATCH;
    } else {
        tile = blockIdx.z;
        rb = blockIdx.x * 128;
    }
    Bt   += (size_t)tile * K * N;
    if constexpr (SPLIT) Btlo += (size_t)tile * K * N;
    bias += (size_t)tile * N;

    __shared__ __align__(16) bf16_t As[128 * 32];
    __shared__ __align__(16) bf16_t Bs[128 * 32];
    __shared__ __align__(16) bf16_t Asl[SPLIT ? 128 * 32 : 8];
    __shared__ __align__(16) bf16_t Bsl[SPLIT ? 128 * 32 : 8];

    const int lane = threadIdx.x & 63;
    const int wave = threadIdx.x >> 6;
    const int wm = wave & 1, wn = wave >> 1;
    const int nb = blockIdx.y * 128;

    size_t aoff[2], boff[2];
#pragma unroll
    for (int r = 0; r < 2; ++r) {
        int seg = r * 4 + wave;
        int row = seg * 16 + (lane & 15);
        int col = (lane >> 4) * 8;
        int arow;
        if constexpr (GATHER) {
            int pos = rb + row;
            if (pos > cnt - 1) pos = cnt - 1;
            arow = permT[pos];
        } else {
            arow = rb + row;
        }
        aoff[r] = (size_t)arow * K + col;
        boff[r] = (size_t)(nb + row) * K + col;
    }

    f32x4 acc[4][4];
#pragma unroll
    for (int i = 0; i < 4; ++i)
#pragma unroll
        for (int j = 0; j < 4; ++j) acc[i][j] = (f32x4){0.f, 0.f, 0.f, 0.f};

    const int lr = lane & 15, lq = lane >> 4;
    const int rdoff = (lq * 16 + lr) * 8;   // element offset within segment

    for (int k0 = 0; k0 < K; k0 += 32) {
#pragma unroll
        for (int r = 0; r < 2; ++r) {
            int seg = r * 4 + wave;
            async_ld16(A  + aoff[r] + k0, &As[seg * 512]);
            async_ld16(Bt + boff[r] + k0, &Bs[seg * 512]);
            if constexpr (SPLIT) {
                async_ld16(Alo  + aoff[r] + k0, &Asl[seg * 512]);
                async_ld16(Btlo + boff[r] + k0, &Bsl[seg * 512]);
            }
        }
        __syncthreads();

        bf16x8 af[4], bfr[4], afl[4], bfl[4];
#pragma unroll
        for (int i = 0; i < 4; ++i) {
            af[i]  = *(const bf16x8*)&As[(wm * 4 + i) * 512 + rdoff];
            bfr[i] = *(const bf16x8*)&Bs[(wn * 4 + i) * 512 + rdoff];
            if constexpr (SPLIT) {
                afl[i] = *(const bf16x8*)&Asl[(wm * 4 + i) * 512 + rdoff];
                bfl[i] = *(const bf16x8*)&Bsl[(wn * 4 + i) * 512 + rdoff];
            }
        }
#pragma unroll
        for (int i = 0; i < 4; ++i)
#pragma unroll
            for (int j = 0; j < 4; ++j) {
                acc[i][j] = mfma16(af[i], bfr[j], acc[i][j]);
                if constexpr (SPLIT) {
                    // hi*lo cross terms only; lo*lo is ~1e-4 absolute, below tolerance
                    acc[i][j] = mfma16(af[i], bfl[j], acc[i][j]);
                    acc[i][j] = mfma16(afl[i], bfr[j], acc[i][j]);
                }
            }
        __syncthreads();
    }

    // epilogue: C row = (lane>>4)*4 + reg, col = lane&15 (m89/m91-verified)
#pragma unroll
    for (int i = 0; i < 4; ++i) {
#pragma unroll
        for (int j = 0; j < 4; ++j) {
#pragma unroll
            for (int r = 0; r < 4; ++r) {
                int m = wm * 64 + i * 16 + lq * 4 + r;
                int n = wn * 64 + j * 16 + lr;
                int pos = rb + m;
                if constexpr (GATHER) { if (pos >= cnt) continue; }
                int grow;
                if constexpr (SCATTER) grow = permT[pos];
                else                   grow = pos;
                int gn = nb + n;
                float v = acc[i][j][r] + bias[gn];
                if constexpr (GELU) v = gelu_exact(v);
                if constexpr (OUTF32) outF[(size_t)grow * N + gn] = v;
                else                  outB[(size_t)grow * N + gn] = (bf16_t)v;
            }
        }
    }
}

// ---------------- router layer2 + argmax + routing lists ----------------
__global__ __launch_bounds__(256) void router2_kernel(
    const float* __restrict__ Hr, const float* __restrict__ Wr2, const float* __restrict__ br2,
    float* __restrict__ outLog, float* __restrict__ outIdx,
    int* __restrict__ counts, int* __restrict__ perm) {
    int lane = threadIdx.x & 63, wave = threadIdx.x >> 6;
    int row = blockIdx.x * 4 + wave;
    const float* h = Hr + (size_t)row * DM;
    float acc[8];
#pragma unroll
    for (int j = 0; j < 8; ++j) acc[j] = 0.f;
    for (int k = lane; k < DM; k += 64) {
        float hv = h[k];
        const float4* w = (const float4*)(Wr2 + (size_t)k * 8);
        float4 w0 = w[0], w1 = w[1];
        acc[0] += hv * w0.x; acc[1] += hv * w0.y; acc[2] += hv * w0.z; acc[3] += hv * w0.w;
        acc[4] += hv * w1.x; acc[5] += hv * w1.y; acc[6] += hv * w1.z; acc[7] += hv * w1.w;
    }
#pragma unroll
    for (int off = 32; off; off >>= 1)
#pragma unroll
        for (int j = 0; j < 8; ++j) acc[j] += __shfl_down(acc[j], off);
    if (lane == 0) {
        float best = -1e30f; int bi = 0;
        float lg[8];
#pragma unroll
        for (int j = 0; j < 8; ++j) {
            float v = (acc[j] + br2[j]) * 2.0f;   // /TEMPERATURE, T=0.5
            lg[j] = v;
            if (v > best) { best = v; bi = j; }   // strict > == first-max (jnp.argmax)
        }
#pragma unroll
        for (int j = 0; j < 8; ++j) outLog[(size_t)row * 8 + j] = lg[j];
        outIdx[row] = (float)bi;
        int p = atomicAdd(&counts[bi], 1);
        perm[bi * BATCH + p] = row;
    }
}

// ---------------- host launch ----------------
extern "C" void kernel_launch(void* const* d_in, const int* in_sizes, int n_in,
                              void* d_out, int out_size, void* d_ws, size_t ws_size,
                              hipStream_t stream) {
    const float* x   = (const float*)d_in[0];
    const float* Wr1 = (const float*)d_in[1];
    const float* br1 = (const float*)d_in[2];
    const float* Wr2 = (const float*)d_in[3];
    const float* br2 = (const float*)d_in[4];
    const float* W1  = (const float*)d_in[5];
    const float* b1  = (const float*)d_in[6];
    const float* W2  = (const float*)d_in[7];
    const float* b2  = (const float*)d_in[8];
    const float* Wo  = (const float*)d_in[9];
    const float* bo  = (const float*)d_in[10];

    char* ws = (char*)d_ws;
    size_t o = 0;
    auto carve = [&](size_t bytes) { char* p = ws + o; o = (o + bytes + 255) & ~(size_t)255; return p; };
    bf16_t* Wr1h = (bf16_t*)carve((size_t)DM * DM * 2);
    bf16_t* Wr1l = (bf16_t*)carve((size_t)DM * DM * 2);
    bf16_t* Wot  = (bf16_t*)carve((size_t)DM * DM * 2);
    bf16_t* W1t  = (bf16_t*)carve((size_t)NTILES * DM * DFF * 2);
    bf16_t* W2t  = (bf16_t*)carve((size_t)NTILES * DM * DFF * 2);
    bf16_t* xh   = (bf16_t*)carve((size_t)BATCH * DM * 2);
    bf16_t* xl   = (bf16_t*)carve((size_t)BATCH * DM * 2);
    bf16_t* H1   = (bf16_t*)carve((size_t)BATCH * DFF * 2);
    bf16_t* sel  = (bf16_t*)carve((size_t)BATCH * DM * 2);
    float*  Hr   = (float*)carve((size_t)BATCH * DM * 4);
    int*    counts = (int*)carve(NTILES * sizeof(int));
    int*    perm   = (int*)carve((size_t)NTILES * BATCH * sizeof(int));
    int*    plan   = (int*)carve(MAXXB * sizeof(int));
    int*    ntotal = (int*)carve(sizeof(int));

    float* outMain = (float*)d_out;
    float* outIdx  = outMain + (size_t)BATCH * DM;
    float* outLog  = outIdx + BATCH;

    hipMemsetAsync(counts, 0, NTILES * sizeof(int), stream);

    cvt_x_kernel<<<BATCH * DM / 4 / 256, 256, 0, stream>>>(x, xh, xl);
    tconv_kernel<true ><<<dim3(DM / 32, DM / 32, 1), 256, 0, stream>>>(Wr1, Wr1h, Wr1l, DM, DM);
    tconv_kernel<false><<<dim3(DM / 32, DM / 32, 1), 256, 0, stream>>>(Wo, Wot, nullptr, DM, DM);
    tconv_kernel<false><<<dim3(DFF / 32, DM / 32, NTILES), 256, 0, stream>>>(W1, W1t, nullptr, DM, DFF);
    tconv_kernel<false><<<dim3(DM / 32, DFF / 32, NTILES), 256, 0, stream>>>(W2, W2t, nullptr, DFF, DM);

    // router layer 1: Hr = gelu(x @ Wr1 + br1), hi/lo split for fp32-class accuracy
    gemm_kernel<true, false, true, false, true><<<dim3(BATCH / 128, DM / 128, 1), 256, 0, stream>>>(
        xh, xl, Wr1h, Wr1l, br1, Hr, nullptr, nullptr, nullptr, nullptr, nullptr, BATCH, DM, DM);

    router2_kernel<<<BATCH / 4, 256, 0, stream>>>(Hr, Wr2, br2, outLog, outIdx, counts, perm);
    plan_kernel<<<1, 64, 0, stream>>>(counts, plan, ntotal);

    // expert layer 1: H1[token] = gelu(x[token] @ W1[t] + b1[t]), gathered+scattered, compacted grid
    gemm_kernel<false, true, true, true, false><<<dim3(MAXXB, DFF / 128, 1), 256, 0, stream>>>(
        xh, nullptr, W1t, nullptr, b1, nullptr, H1, perm, counts, plan, ntotal, BATCH, DFF, DM);

    // expert layer 2: sel[token] = H1[token] @ W2[t] + b2[t]
    gemm_kernel<false, true, false, true, false><<<dim3(MAXXB, DM / 128, 1), 256, 0, stream>>>(
        H1, nullptr, W2t, nullptr, b2, nullptr, sel, perm, counts, plan, ntotal, BATCH, DM, DFF);

    // output projection: out = sel @ Wo + bo
    gemm_kernel<false, false, false, false, true><<<dim3(BATCH / 128, DM / 128, 1), 256, 0, stream>>>(
        sel, nullptr, Wot, nullptr, bo, outMain, nullptr, nullptr, nullptr, nullptr, nullptr, BATCH, DM, DM);
}